// Round 2
// baseline (321.882 us; speedup 1.0000x reference)
//
#include <hip/hip_runtime.h>
#include <hip/hip_bf16.h>

#define M_DIM 16384
#define N_DIM 1000
#define N_PAD 1024
#define K_DIM 2048
#define INV_F (1.0f / 2048.0f)

#define BM 128
#define BN 128
#define BK 32

typedef __bf16 bf16v8 __attribute__((ext_vector_type(8)));
typedef __bf16 bf16v4 __attribute__((ext_vector_type(4)));
typedef float  f32v4  __attribute__((ext_vector_type(4)));
typedef unsigned int u32;

// async global->LDS, 16B per lane (guide: width=16 is the fast path, m97)
__device__ __forceinline__ void gload_lds16(const void* g, void* l) {
  __builtin_amdgcn_global_load_lds(
      (const __attribute__((address_space(1))) u32*)g,
      (__attribute__((address_space(3))) u32*)l, 16, 0, 0);
}

// ---------------------------------------------------------------------------
// Conversion: fp32 row -> bf16 row (+ fp32 sum of squares). One block per row,
// 256 threads, 8 elems/thread. Rows >= nvalid are zero-padded (for w pad),
// including w2 = 0, so the GEMM may safely read the padded region even though
// the harness re-poisons d_ws with 0xAA before every timed launch.
// ---------------------------------------------------------------------------
__global__ __launch_bounds__(256) void cvt_rows(
    const float* __restrict__ src, __bf16* __restrict__ dst,
    float* __restrict__ sq, int nvalid)
{
  const int row = blockIdx.x;
  const int t = threadIdx.x;
  __bf16* dr = dst + (size_t)row * K_DIM;
  float s = 0.0f;

  if (row < nvalid) {
    const float4* sr = (const float4*)(src + (size_t)row * K_DIM);
    float4 a = sr[t];         // first half of row
    float4 b = sr[t + 256];   // second half
    s = a.x*a.x + a.y*a.y + a.z*a.z + a.w*a.w
      + b.x*b.x + b.y*b.y + b.z*b.z + b.w*b.w;
    bf16v4 oa, ob;
    oa[0]=(__bf16)a.x; oa[1]=(__bf16)a.y; oa[2]=(__bf16)a.z; oa[3]=(__bf16)a.w;
    ob[0]=(__bf16)b.x; ob[1]=(__bf16)b.y; ob[2]=(__bf16)b.z; ob[3]=(__bf16)b.w;
    ((bf16v4*)dr)[t]       = oa;
    ((bf16v4*)dr)[t + 256] = ob;
  } else {
    bf16v4 z;
    #pragma unroll
    for (int i = 0; i < 4; ++i) z[i] = (__bf16)0.0f;
    ((bf16v4*)dr)[t]       = z;
    ((bf16v4*)dr)[t + 256] = z;
  }

  // block reduction of s
  #pragma unroll
  for (int off = 32; off > 0; off >>= 1) s += __shfl_down(s, off, 64);
  __shared__ float red[4];
  if ((t & 63) == 0) red[t >> 6] = s;
  __syncthreads();
  if (t == 0) sq[row] = red[0] + red[1] + red[2] + red[3];
}

// ---------------------------------------------------------------------------
// bf16 MFMA GEMM (m97 structure): 128x128 tile, BK=32, 4 waves (2x2), each
// wave 64x64 = 4x4 fragments of 16x16x32. B input is w [C][F] row-major,
// which is exactly the verified B^T ("gemm_bt") layout. Fused epilogue:
//   out[r][c] = (2*acc - x2[r] - w2[c]) * (1/F)
// ---------------------------------------------------------------------------
__global__ __launch_bounds__(256) void gemm_ep(
    const __bf16* __restrict__ A, const __bf16* __restrict__ B,
    const float* __restrict__ x2, const float* __restrict__ w2,
    float* __restrict__ out)
{
  __shared__ __bf16 As[BM * BK];   // 8 KB, linear [128][32]
  __shared__ __bf16 Bs[BN * BK];   // 8 KB

  const int bid = blockIdx.x;
  const int bn = bid & 7;          // 8 col tiles (N_PAD/BN) — fastest varying
  const int bm = bid >> 3;         // 128 row tiles
  const int brow = bm * BM;
  const int bcol = bn * BN;

  const int tid = threadIdx.x;
  const int lane = tid & 63;
  const int wid = tid >> 6;
  const int wm = wid >> 1;         // 0..1
  const int wn = wid & 1;          // 0..1

  const int lr = lane & 15;        // fragment row (A) / col (B)
  const int lk = (lane >> 4) * 8;  // k offset within BK

  f32v4 acc[4][4];
  #pragma unroll
  for (int m = 0; m < 4; ++m)
    #pragma unroll
    for (int n = 0; n < 4; ++n)
      acc[m][n] = (f32v4){0.f, 0.f, 0.f, 0.f};

  // staging: 512 lane-loads of 16B cover one 128x32 bf16 tile; 256 threads
  // -> 2 rounds each for A and B. LDS dest is linear (wave-uniform base +
  // lane*16), global src is per-lane — satisfies the gload_lds contract.
  for (int kt = 0; kt < K_DIM / BK; ++kt) {
    const int kbase = kt * BK;
    #pragma unroll
    for (int r = 0; r < 2; ++r) {
      const int li = r * 256 + tid;
      const int trow = li >> 2;
      const int tcol = (li & 3) * 8;
      gload_lds16(A + (size_t)(brow + trow) * K_DIM + kbase + tcol, As + li * 8);
      gload_lds16(B + (size_t)(bcol + trow) * K_DIM + kbase + tcol, Bs + li * 8);
    }
    __syncthreads();   // compiler drains vmcnt(0) before s_barrier

    bf16v8 a[4], b[4];
    #pragma unroll
    for (int m = 0; m < 4; ++m)
      a[m] = *(const bf16v8*)(As + (wm * 64 + m * 16 + lr) * BK + lk);
    #pragma unroll
    for (int n = 0; n < 4; ++n)
      b[n] = *(const bf16v8*)(Bs + (wn * 64 + n * 16 + lr) * BK + lk);

    #pragma unroll
    for (int m = 0; m < 4; ++m)
      #pragma unroll
      for (int n = 0; n < 4; ++n)
        acc[m][n] = __builtin_amdgcn_mfma_f32_16x16x32_bf16(a[m], b[n], acc[m][n], 0, 0, 0);

    __syncthreads();
  }

  // epilogue: C/D layout col = lane&15, row = (lane>>4)*4 + j  (m89/m91)
  const int r0 = brow + wm * 64 + (lane >> 4) * 4;
  const int c0 = bcol + wn * 64 + lr;
  #pragma unroll
  for (int n = 0; n < 4; ++n) {
    const int col = c0 + n * 16;
    if (col >= N_DIM) continue;
    const float w2c = w2[col];
    #pragma unroll
    for (int m = 0; m < 4; ++m) {
      const int row = r0 + m * 16;
      #pragma unroll
      for (int j = 0; j < 4; ++j) {
        float v = (2.0f * acc[m][n][j] - x2[row + j] - w2c) * INV_F;
        out[(size_t)(row + j) * N_DIM + col] = v;
      }
    }
  }
}

// ---------------------------------------------------------------------------
// Safety net if ws_size is too small for the bf16 staging buffers: direct
// fp32 computation (slow but correct, no workspace).
// ---------------------------------------------------------------------------
__global__ __launch_bounds__(256) void fallback_fp32(
    const float* __restrict__ x, const float* __restrict__ w,
    float* __restrict__ out)
{
  long idx = (long)blockIdx.x * 256 + threadIdx.x;
  if (idx >= (long)M_DIM * N_DIM) return;
  int row = (int)(idx / N_DIM);
  int col = (int)(idx % N_DIM);
  const float4* xr = (const float4*)(x + (size_t)row * K_DIM);
  const float4* wr = (const float4*)(w + (size_t)col * K_DIM);
  float s = 0.f;
  for (int i = 0; i < K_DIM / 4; ++i) {
    float4 a = xr[i], b = wr[i];
    float d0 = a.x - b.x, d1 = a.y - b.y, d2 = a.z - b.z, d3 = a.w - b.w;
    s += d0*d0 + d1*d1 + d2*d2 + d3*d3;
  }
  out[idx] = -s * INV_F;
}

extern "C" void kernel_launch(void* const* d_in, const int* in_sizes, int n_in,
                              void* d_out, int out_size, void* d_ws, size_t ws_size,
                              hipStream_t stream) {
  const float* x = (const float*)d_in[0];
  const float* w = (const float*)d_in[1];
  float* out = (float*)d_out;

  const size_t need = (size_t)M_DIM * K_DIM * 2   // x bf16
                    + (size_t)N_PAD * K_DIM * 2   // w bf16 (padded)
                    + (size_t)M_DIM * 4           // x2
                    + (size_t)N_PAD * 4;          // w2
  if (ws_size < need) {
    const long total = (long)M_DIM * N_DIM;
    fallback_fp32<<<(int)((total + 255) / 256), 256, 0, stream>>>(x, w, out);
    return;
  }

  __bf16* xb = (__bf16*)d_ws;
  __bf16* wb = xb + (size_t)M_DIM * K_DIM;
  float* x2 = (float*)(wb + (size_t)N_PAD * K_DIM);
  float* w2 = x2 + M_DIM;

  cvt_rows<<<M_DIM, 256, 0, stream>>>(x, xb, x2, M_DIM);
  cvt_rows<<<N_PAD, 256, 0, stream>>>(w, wb, w2, N_DIM);
  gemm_ep<<<(M_DIM / BM) * (N_PAD / BN), 256, 0, stream>>>(xb, wb, x2, w2, out);
}

// Round 3
// 287.327 us; speedup vs baseline: 1.1203x; 1.1203x over previous
//
#include <hip/hip_runtime.h>
#include <hip/hip_bf16.h>

#define M_DIM 16384
#define N_DIM 1000
#define N_PAD 1024
#define K_DIM 2048
#define INV_F (1.0f / 2048.0f)

#define BM 256
#define BN 256
#define BK 32
#define NT (K_DIM / BK)            // 64 K-steps
#define SLOT_ELEMS (2 * BM * BK)   // A + B per ring slot, bf16 elements (16384)

typedef __bf16 bf16v8 __attribute__((ext_vector_type(8)));
typedef __bf16 bf16v4 __attribute__((ext_vector_type(4)));
typedef float  f32v4  __attribute__((ext_vector_type(4)));
typedef unsigned int u32;

// async global->LDS, 16B per lane (width=16 fast path, m97)
__device__ __forceinline__ void gload_lds16(const void* g, void* l) {
  __builtin_amdgcn_global_load_lds(
      (const __attribute__((address_space(1))) u32*)g,
      (__attribute__((address_space(3))) u32*)l, 16, 0, 0);
}

// ---------------------------------------------------------------------------
// fp32 row -> bf16 row + fp32 sum-of-squares. ONE WAVE PER ROW: no LDS, no
// __syncthreads. 4 rows per 256-thread block. Lane reads 2 adjacent float4
// (32B) x4 passes, writes one bf16v8 (16B) per pass. Rows >= nvalid zeroed
// (w padding; d_ws is re-poisoned 0xAA before every timed launch).
// ---------------------------------------------------------------------------
__global__ __launch_bounds__(256) void cvt_rows(
    const float* __restrict__ src, __bf16* __restrict__ dst,
    float* __restrict__ sq, int nvalid)
{
  const int row  = blockIdx.x * 4 + (threadIdx.x >> 6);
  const int lane = threadIdx.x & 63;
  const float4* sr = (const float4*)(src + (size_t)row * K_DIM);
  bf16v8* dr = (bf16v8*)(dst + (size_t)row * K_DIM);
  float s = 0.0f;
  if (row < nvalid) {
    #pragma unroll
    for (int i = 0; i < 4; ++i) {
      float4 a = sr[2 * lane + i * 128];
      float4 b = sr[2 * lane + 1 + i * 128];
      s += a.x*a.x + a.y*a.y + a.z*a.z + a.w*a.w
         + b.x*b.x + b.y*b.y + b.z*b.z + b.w*b.w;
      bf16v8 o;
      o[0]=(__bf16)a.x; o[1]=(__bf16)a.y; o[2]=(__bf16)a.z; o[3]=(__bf16)a.w;
      o[4]=(__bf16)b.x; o[5]=(__bf16)b.y; o[6]=(__bf16)b.z; o[7]=(__bf16)b.w;
      dr[lane + i * 64] = o;
    }
  } else {
    bf16v8 z;
    #pragma unroll
    for (int k = 0; k < 8; ++k) z[k] = (__bf16)0.0f;
    #pragma unroll
    for (int i = 0; i < 4; ++i) dr[lane + i * 64] = z;
  }
  #pragma unroll
  for (int off = 32; off > 0; off >>= 1) s += __shfl_down(s, off, 64);
  if (lane == 0) sq[row] = s;
}

// ---------------------------------------------------------------------------
// 256x256 bf16 MFMA GEMM, BK=32, 3-slot LDS ring (96 KB), counted vmcnt(4).
// 512 threads = 8 waves (2M x 4N), per-wave 128x64 = 8x4 fragments 16x16x32.
// Ring discipline per K-step t (reading slot t%3):
//   - issue 4 gload_lds for tile t+2 into slot (t+2)%3  [freed at t-1's barrier]
//   - ds_read fragments, 32 MFMA
//   - lgkmcnt(0) drain (WAR safety) + sched_barrier (rule #18)
//   - vmcnt(4): tile t+1 landed, tile t+2 stays in flight  [T4: never 0]
//   - raw s_barrier (no compiler vmcnt(0) drain)
// Epilogue fuses: out[r][c] = (2*acc - x2[r] - w2[c]) / F, guard c < 1000.
// ---------------------------------------------------------------------------
__global__ __launch_bounds__(512, 2) void gemm_ep(
    const __bf16* __restrict__ A, const __bf16* __restrict__ B,
    const float* __restrict__ x2, const float* __restrict__ w2,
    float* __restrict__ out)
{
  __shared__ __bf16 lds[3 * SLOT_ELEMS];   // 96 KB

  // T1: bijective XCD swizzle (256 blocks % 8 == 0). HW round-robins bid
  // over 8 XCDs; remap so each XCD owns 32 contiguous tiles = 8 A-panels.
  const int bid = blockIdx.x;
  const int swz = (bid & 7) * 32 + (bid >> 3);
  const int bm = swz >> 2;          // 64 row tiles
  const int bn = swz & 3;           // 4 col tiles, fastest (A-panel reuse)
  const int brow = bm * BM;
  const int bcol = bn * BN;

  const int tid  = threadIdx.x;
  const int lane = tid & 63;
  const int wid  = tid >> 6;
  const int wm   = wid >> 2;        // 0..1
  const int wn   = wid & 3;         // 0..3

  // staging source: thread covers row (tid>>2) and row+128, 16B at col (tid&3)*8
  const int srow = tid >> 2;
  const int scol = (tid & 3) * 8;
  const __bf16* gA0 = A + (size_t)(brow + srow) * K_DIM + scol;
  const __bf16* gA1 = gA0 + (size_t)128 * K_DIM;
  const __bf16* gB0 = B + (size_t)(bcol + srow) * K_DIM + scol;
  const __bf16* gB1 = gB0 + (size_t)128 * K_DIM;

  // staging dest element offsets within a slot (linear: uniform base + lane*16B)
  const int dA0 = tid * 8;
  const int dA1 = (512 + tid) * 8;
  const int dB0 = BM * BK + tid * 8;
  const int dB1 = BM * BK + (512 + tid) * 8;

  f32v4 acc[8][4];
  #pragma unroll
  for (int m = 0; m < 8; ++m)
    #pragma unroll
    for (int n = 0; n < 4; ++n)
      acc[m][n] = (f32v4){0.f, 0.f, 0.f, 0.f};

  const int lr = lane & 15;
  const int lk = (lane >> 4) * 8;
  const int aOff = (wm * 128 + lr) * BK + lk;            // + m*16*BK
  const int bOff = BM * BK + (wn * 64 + lr) * BK + lk;   // + n*16*BK

  // prologue: stage tiles 0 and 1; wait tile 0 (vmcnt(4): tile 1 in flight)
  {
    __bf16* s0 = lds;
    gload_lds16(gA0, s0 + dA0); gload_lds16(gA1, s0 + dA1);
    gload_lds16(gB0, s0 + dB0); gload_lds16(gB1, s0 + dB1);
    __bf16* s1 = lds + SLOT_ELEMS;
    gload_lds16(gA0 + BK, s1 + dA0); gload_lds16(gA1 + BK, s1 + dA1);
    gload_lds16(gB0 + BK, s1 + dB0); gload_lds16(gB1 + BK, s1 + dB1);
  }
  asm volatile("s_waitcnt vmcnt(4)" ::: "memory");
  __builtin_amdgcn_s_barrier();
  asm volatile("" ::: "memory");

  int slot = 0;
  #pragma unroll 1
  for (int t = 0; t < NT; ++t) {
    if (t + 2 < NT) {
      int s2 = slot + 2; if (s2 >= 3) s2 -= 3;
      __bf16* sb = lds + s2 * SLOT_ELEMS;
      const int ko = (t + 2) * BK;
      gload_lds16(gA0 + ko, sb + dA0);
      gload_lds16(gA1 + ko, sb + dA1);
      gload_lds16(gB0 + ko, sb + dB0);
      gload_lds16(gB1 + ko, sb + dB1);
    }

    const __bf16* sb = lds + slot * SLOT_ELEMS;
    bf16v8 a[8], b[4];
    #pragma unroll
    for (int m = 0; m < 8; ++m)
      a[m] = *(const bf16v8*)(sb + aOff + m * 16 * BK);
    #pragma unroll
    for (int n = 0; n < 4; ++n)
      b[n] = *(const bf16v8*)(sb + bOff + n * 16 * BK);

    #pragma unroll
    for (int m = 0; m < 8; ++m)
      #pragma unroll
      for (int n = 0; n < 4; ++n)
        acc[m][n] = __builtin_amdgcn_mfma_f32_16x16x32_bf16(a[m], b[n], acc[m][n], 0, 0, 0);

    // WAR: all my LDS reads drained before crossing the barrier
    asm volatile("s_waitcnt lgkmcnt(0)" ::: "memory");
    __builtin_amdgcn_sched_barrier(0);
    // RAW: tile t+1's loads (mine) landed; tile t+2's stay in flight
    if (t + 2 < NT) asm volatile("s_waitcnt vmcnt(4)" ::: "memory");
    else            asm volatile("s_waitcnt vmcnt(0)" ::: "memory");
    __builtin_amdgcn_s_barrier();
    asm volatile("" ::: "memory");

    slot = (slot == 2) ? 0 : slot + 1;
  }

  // epilogue: C/D layout col = lane&15, row = (lane>>4)*4 + j  (m89/m91)
  const int r0 = brow + wm * 128 + (lane >> 4) * 4;
  const int c0 = bcol + wn * 64 + lr;
  #pragma unroll
  for (int m = 0; m < 8; ++m) {
    const int row = r0 + m * 16;
    float xr[4];
    #pragma unroll
    for (int j = 0; j < 4; ++j) xr[j] = x2[row + j];
    #pragma unroll
    for (int n = 0; n < 4; ++n) {
      const int col = c0 + n * 16;
      if (col < N_DIM) {
        const float w2c = w2[col];
        #pragma unroll
        for (int j = 0; j < 4; ++j)
          out[(size_t)(row + j) * N_DIM + col] =
              (2.0f * acc[m][n][j] - xr[j] - w2c) * INV_F;
      }
    }
  }
}

// ---------------------------------------------------------------------------
// Safety net if ws_size is too small: direct fp32 computation.
// ---------------------------------------------------------------------------
__global__ __launch_bounds__(256) void fallback_fp32(
    const float* __restrict__ x, const float* __restrict__ w,
    float* __restrict__ out)
{
  long idx = (long)blockIdx.x * 256 + threadIdx.x;
  if (idx >= (long)M_DIM * N_DIM) return;
  int row = (int)(idx / N_DIM);
  int col = (int)(idx % N_DIM);
  const float4* xr = (const float4*)(x + (size_t)row * K_DIM);
  const float4* wr = (const float4*)(w + (size_t)col * K_DIM);
  float s = 0.f;
  for (int i = 0; i < K_DIM / 4; ++i) {
    float4 a = xr[i], b = wr[i];
    float d0 = a.x - b.x, d1 = a.y - b.y, d2 = a.z - b.z, d3 = a.w - b.w;
    s += d0*d0 + d1*d1 + d2*d2 + d3*d3;
  }
  out[idx] = -s * INV_F;
}

extern "C" void kernel_launch(void* const* d_in, const int* in_sizes, int n_in,
                              void* d_out, int out_size, void* d_ws, size_t ws_size,
                              hipStream_t stream) {
  const float* x = (const float*)d_in[0];
  const float* w = (const float*)d_in[1];
  float* out = (float*)d_out;

  const size_t need = (size_t)M_DIM * K_DIM * 2
                    + (size_t)N_PAD * K_DIM * 2
                    + (size_t)M_DIM * 4
                    + (size_t)N_PAD * 4;
  if (ws_size < need) {
    const long total = (long)M_DIM * N_DIM;
    fallback_fp32<<<(int)((total + 255) / 256), 256, 0, stream>>>(x, w, out);
    return;
  }

  __bf16* xb = (__bf16*)d_ws;
  __bf16* wb = xb + (size_t)M_DIM * K_DIM;
  float* x2 = (float*)(wb + (size_t)N_PAD * K_DIM);
  float* w2 = x2 + M_DIM;

  cvt_rows<<<M_DIM / 4, 256, 0, stream>>>(x, xb, x2, M_DIM);
  cvt_rows<<<N_PAD / 4, 256, 0, stream>>>(w, wb, w2, N_DIM);
  gemm_ep<<<(M_DIM / BM) * (N_PAD / BN), 512, 0, stream>>>(xb, wb, x2, w2, out);
}